// Round 4
// baseline (150.026 us; speedup 1.0000x reference)
//
#include <hip/hip_runtime.h>
#include <math.h>

#define NN 2048   // nodes
#define IF 128    // in features
#define NH 4      // heads
#define NF 16     // hidden per head
#define OF 64     // NH*NF
#define NTILE (NN / 64)   // 32 j-tiles of 64
#define LOG2E 1.44269504f

__device__ __forceinline__ float rfl(float x) {   // force wave-uniform value into SGPR
    return __int_as_float(__builtin_amdgcn_readfirstlane(__float_as_int(x)));
}

// ---------------- Kernel 1: projections (head-major) + attention-bias precompute ----------------
// grid NN/2, block 256 (4 waves). wave w -> node (blockIdx.x*2 + (w>>1)), matrix (w&1).
// Writes glt/grt [NH][NN][NF] (head-major), and base-2-scaled biases:
//   cj6[h][j] = 0.6*log2e*sum_f aw_f*glt[h,j,f],  bi6[h][i] likewise from grt.
__global__ __launch_bounds__(256) void proj_kernel(const float* __restrict__ h,
                                                   const float* __restrict__ Wl,
                                                   const float* __restrict__ Wr,
                                                   const float* __restrict__ attn_w,
                                                   float* __restrict__ glt,
                                                   float* __restrict__ grt,
                                                   float* __restrict__ cj6,
                                                   float* __restrict__ bi6) {
    const int t    = threadIdx.x;
    const int w    = t >> 6, lane = t & 63;
    const int il   = w >> 1, which = w & 1;          // which: 0 = W_l, 1 = W_r
    const int i    = blockIdx.x * 2 + il;

    __shared__ float hs[2][IF];
    hs[t >> 7][t & 127] = h[(blockIdx.x * 2 + (t >> 7)) * IF + (t & 127)];
    __syncthreads();

    const float* W = which ? Wr : Wl;
    float acc = 0.f;
    #pragma unroll
    for (int k = 0; k < IF; ++k)
        acc = fmaf(hs[il][k], W[k * OF + lane], acc);   // coalesced W read per wave

    // head-major write: g[h][i][f], lane = h*16+f
    float* g = which ? grt : glt;
    g[(lane >> 4) * (NN * NF) + i * NF + (lane & 15)] = acc;

    // per-head dot with attn_w: reduce within each 16-lane head group
    float v = acc * attn_w[lane & 15];
    v += __shfl_xor(v, 1);
    v += __shfl_xor(v, 2);
    v += __shfl_xor(v, 4);
    v += __shfl_xor(v, 8);
    if ((lane & 15) == 0) {
        float* dst = which ? bi6 : cj6;
        dst[(lane >> 4) * NN + i] = 0.6f * LOG2E * v;
    }
}

// ---------------- Kernel 2: fused flash-style GAT ----------------
// grid NN/2, block 512 (8 waves). wave wid -> head (wid&3), node i = bx*2 + (wid>>2).
// lane = j within tile; per-lane online softmax in base-2 (m,l,acc[16]); merge at end.
// launch_bounds(512, 4): 4 waves/EU -> 128-VGPR cap so the depth-2 register
// pipeline (gA/rA/gB/rB = 64 VGPR) actually stays in flight. No in-loop barrier.
__global__ __launch_bounds__(512, 4) void gat_kernel(const float* __restrict__ glt,
                                                     const float* __restrict__ grt,
                                                     const float* __restrict__ cj6,
                                                     const float* __restrict__ bi6,
                                                     const int*   __restrict__ adj,
                                                     const float* __restrict__ attn_w,
                                                     float*       __restrict__ out) {
    const int t    = threadIdx.x;
    const int wid  = t >> 6, lane = t & 63;
    const int h    = wid & 3;
    const int i    = blockIdx.x * 2 + (wid >> 2);

    // wave-uniform values -> SGPR. aw pre-scaled by 0.4*log2e (base-2 softmax).
    float aw_s[NF], gr_s[NF];
    #pragma unroll
    for (int f = 0; f < NF; ++f) {
        aw_s[f] = rfl(attn_w[f]) * (0.4f * LOG2E);
        gr_s[f] = rfl(grt[h * (NN * NF) + i * NF + f]);
    }
    const float bi = rfl(bi6[h * NN + i]);

    const float* glh = glt + (size_t)h * NN * NF;   // + j*16: per-lane CONTIGUOUS 64B
    const float* grh = grt + (size_t)h * NN * NF;
    const float* cjh = cj6 + h * NN;
    const int*   arw = adj + (size_t)i * NN;

    float m = -INFINITY, l = 0.f;    // m in base-2 units
    float acc[NF];
    #pragma unroll
    for (int f = 0; f < NF; ++f) acc[f] = 0.f;

    float4 gA[4], rA[4], gB[4], rB[4];
    float  cjA, cjB;
    int    adA, adB;

#define LOADT(tt, gg, rr, cj, ad)                                          \
    {                                                                      \
        const int j = (tt) * 64 + lane;                                    \
        const float4* pg = (const float4*)(glh + (size_t)j * NF);          \
        const float4* pr = (const float4*)(grh + (size_t)j * NF);          \
        gg[0] = pg[0]; gg[1] = pg[1]; gg[2] = pg[2]; gg[3] = pg[3];        \
        rr[0] = pr[0]; rr[1] = pr[1]; rr[2] = pr[2]; rr[3] = pr[3];        \
        cj = cjh[j]; ad = arw[j];                                          \
    }

#define STEPT(gg, rr, cj, ad)                                              \
    {                                                                      \
        float s = 0.f;                                                     \
        _Pragma("unroll")                                                  \
        for (int q = 0; q < 4; ++q) {                                      \
            const float4 v = gg[q];                                        \
            s = fmaf(fabsf(v.x + gr_s[q * 4 + 0]), aw_s[q * 4 + 0], s);    \
            s = fmaf(fabsf(v.y + gr_s[q * 4 + 1]), aw_s[q * 4 + 1], s);    \
            s = fmaf(fabsf(v.z + gr_s[q * 4 + 2]), aw_s[q * 4 + 2], s);    \
            s = fmaf(fabsf(v.w + gr_s[q * 4 + 3]), aw_s[q * 4 + 3], s);    \
        }                                                                  \
        const float e2 = s + (bi + cj);       /* base-2 logit */           \
        const bool msk = (ad != 0);                                        \
        const float ee = msk ? e2 : -INFINITY;                             \
        if (__any(ee > m + 11.5417f)) {       /* rare: deferred rescale */ \
            const bool  c     = ee > m + 11.5417f;                         \
            const float alpha = c ? __builtin_amdgcn_exp2f(m - ee) : 1.f;  \
            m = c ? ee : m;                                                \
            l *= alpha;                                                    \
            _Pragma("unroll")                                              \
            for (int f = 0; f < NF; ++f) acc[f] *= alpha;                  \
        }                                                                  \
        const float p = msk ? __builtin_amdgcn_exp2f(e2 - m) : 0.f;        \
        l += p;                                                            \
        _Pragma("unroll")                                                  \
        for (int q = 0; q < 4; ++q) {                                      \
            const float4 v = rr[q];                                        \
            acc[q * 4 + 0] = fmaf(p, v.x, acc[q * 4 + 0]);                 \
            acc[q * 4 + 1] = fmaf(p, v.y, acc[q * 4 + 1]);                 \
            acc[q * 4 + 2] = fmaf(p, v.z, acc[q * 4 + 2]);                 \
            acc[q * 4 + 3] = fmaf(p, v.w, acc[q * 4 + 3]);                 \
        }                                                                  \
    }

    // ping-pong register double buffer over 32 tiles; no barrier (avoid convoys,
    // let waves drift — loads are contiguous 64B/lane, L2 has headroom)
    LOADT(0, gA, rA, cjA, adA);
    for (int tt = 0; tt < NTILE; tt += 2) {
        LOADT(tt + 1, gB, rB, cjB, adB);
        STEPT(gA, rA, cjA, adA);
        const int nx = (tt + 2 < NTILE) ? tt + 2 : NTILE - 1;  // clamped redundant load on last iter
        LOADT(nx, gA, rA, cjA, adA);
        STEPT(gB, rB, cjB, adB);
    }
#undef LOADT
#undef STEPT

    // ---- merge (m, l, acc) across the 64 lanes ----
    float M = m;
    #pragma unroll
    for (int off = 32; off; off >>= 1) M = fmaxf(M, __shfl_xor(M, off));
    const float sc = (m > -INFINITY) ? __builtin_amdgcn_exp2f(m - M) : 0.f;
    l *= sc;
    #pragma unroll
    for (int off = 32; off; off >>= 1) l += __shfl_xor(l, off);

    #pragma unroll
    for (int f = 0; f < NF; ++f) {
        float a = acc[f] * sc;
        a += __shfl_xor(a, 32);
        a += __shfl_xor(a, 16);
        acc[f] = a;      // lanes r, r+16, r+32, r+48 now hold identical group sums
    }

    __shared__ float red[8][16][NF + 1];
    if (lane < 16) {
        #pragma unroll
        for (int f = 0; f < NF; ++f) red[wid][lane][f] = acc[f];
    }
    __syncthreads();
    if (lane < NF) {
        float s = 0.f;
        #pragma unroll
        for (int r = 0; r < 16; ++r) s += red[wid][r][lane];
        out[i * OF + h * NF + lane] = (l > 0.f) ? s / l : 0.f;   // l==0 -> nan_to_num(0)
    }
}

extern "C" void kernel_launch(void* const* d_in, const int* in_sizes, int n_in,
                              void* d_out, int out_size, void* d_ws, size_t ws_size,
                              hipStream_t stream) {
    const float* h      = (const float*)d_in[0];
    const int*   adj    = (const int*)d_in[1];
    const float* W_l    = (const float*)d_in[2];
    const float* W_r    = (const float*)d_in[3];
    const float* attn_w = (const float*)d_in[4];
    float*       out    = (float*)d_out;

    float* glt = (float*)d_ws;                    // [NH][NN][NF]
    float* grt = glt + (size_t)NN * OF;           // [NH][NN][NF]
    float* cj6 = grt + (size_t)NN * OF;           // [NH][NN]
    float* bi6 = cj6 + (size_t)NH * NN;           // [NH][NN]

    proj_kernel<<<NN / 2, 256, 0, stream>>>(h, W_l, W_r, attn_w, glt, grt, cj6, bi6);
    gat_kernel<<<NN / 2, 512, 0, stream>>>(glt, grt, cj6, bi6, adj, attn_w, out);
}

// Round 5
// 83.378 us; speedup vs baseline: 1.7993x; 1.7993x over previous
//
#include <hip/hip_runtime.h>
#include <math.h>

#define NN 2048   // nodes
#define IF 128    // in features
#define NH 4      // heads
#define NF 16     // hidden per head
#define OF 64     // NH*NF
#define NTILE (NN / 64)   // 32 j-tiles of 64
#define LOG2E 1.44269504f

__device__ __forceinline__ float rfl(float x) {   // force wave-uniform value into SGPR
    return __int_as_float(__builtin_amdgcn_readfirstlane(__float_as_int(x)));
}

// ---------------- Kernel 1: projections (head-major) + attention-bias precompute ----------------
// Writes glt/grt [NH][NN][NF] (head-major), and base-2-scaled biases:
//   cj6[h][j] = 0.6*log2e*sum_f aw_f*glt[h,j,f],  bi6[h][i] likewise from grt.
__global__ __launch_bounds__(256) void proj_kernel(const float* __restrict__ h,
                                                   const float* __restrict__ Wl,
                                                   const float* __restrict__ Wr,
                                                   const float* __restrict__ attn_w,
                                                   float* __restrict__ glt,
                                                   float* __restrict__ grt,
                                                   float* __restrict__ cj6,
                                                   float* __restrict__ bi6) {
    const int t    = threadIdx.x;
    const int w    = t >> 6, lane = t & 63;
    const int il   = w >> 1, which = w & 1;          // which: 0 = W_l, 1 = W_r
    const int i    = blockIdx.x * 2 + il;

    __shared__ float hs[2][IF];
    hs[t >> 7][t & 127] = h[(blockIdx.x * 2 + (t >> 7)) * IF + (t & 127)];
    __syncthreads();

    const float* W = which ? Wr : Wl;
    float acc = 0.f;
    #pragma unroll
    for (int k = 0; k < IF; ++k)
        acc = fmaf(hs[il][k], W[k * OF + lane], acc);   // coalesced W read per wave

    // head-major write: g[h][i][f], lane = h*16+f
    float* g = which ? grt : glt;
    g[(lane >> 4) * (NN * NF) + i * NF + (lane & 15)] = acc;

    // per-head dot with attn_w: reduce within each 16-lane head group
    float v = acc * attn_w[lane & 15];
    v += __shfl_xor(v, 1);
    v += __shfl_xor(v, 2);
    v += __shfl_xor(v, 4);
    v += __shfl_xor(v, 8);
    if ((lane & 15) == 0) {
        float* dst = which ? bi6 : cj6;
        dst[(lane >> 4) * NN + i] = 0.6f * LOG2E * v;
    }
}

// ---------------- Kernel 2: fused flash-style GAT, 2 nodes per wave ----------------
// grid NH*128 = 512 blocks, block 512 (8 waves, ALL same head h = bx>>7).
// Block covers 16 consecutive nodes; wave wid owns i0 = grp*16 + wid*2 and i0+1.
// All 8 waves read the SAME g-tile per step -> L1 captures 7/8 of reads.
// Per-lane online softmax in base-2; serial loop, latency hidden by TLP
// (4 waves/SIMD x ~230 cy compute per step).
__global__ __launch_bounds__(512, 4) void gat_kernel(const float* __restrict__ glt,
                                                     const float* __restrict__ grt,
                                                     const float* __restrict__ cj6,
                                                     const float* __restrict__ bi6,
                                                     const int*   __restrict__ adj,
                                                     float*       __restrict__ out) {
    const int t    = threadIdx.x;
    const int wid  = t >> 6, lane = t & 63;
    const int h    = blockIdx.x >> 7;          // 128 node-groups per head
    const int grp  = blockIdx.x & 127;
    const int i0   = grp * 16 + wid * 2;
    const int i1   = i0 + 1;

    // wave-uniform values -> SGPR. aw pre-scaled by 0.4*log2e (base-2 softmax).
    const float* awp = cj6 - NH * NN - NF;     // not used; placeholder removed below
    (void)awp;

    float aw_s[NF], g0_s[NF], g1_s[NF];
    #pragma unroll
    for (int f = 0; f < NF; ++f) {
        g0_s[f] = rfl(grt[h * (NN * NF) + i0 * NF + f]);
        g1_s[f] = rfl(grt[h * (NN * NF) + i1 * NF + f]);
    }
    // attn_w scaled: stored by proj in bi6 tail? No — recompute from global attn_w is
    // not passed; instead scale is folded here from cj6/bi6 convention: we need raw aw.
    // (aw passed via out-of-band buffer aw_scaled, see launch.)
    const float* aws = (const float*)(bi6 + NH * NN);   // [NF] = attn_w * 0.4*log2e
    #pragma unroll
    for (int f = 0; f < NF; ++f) aw_s[f] = rfl(aws[f]);

    const float bi0 = rfl(bi6[h * NN + i0]);
    const float bi1 = rfl(bi6[h * NN + i1]);

    const float* glh = glt + (size_t)h * NN * NF;   // + j*16: per-lane CONTIGUOUS 64B
    const float* grh = grt + (size_t)h * NN * NF;
    const float* cjh = cj6 + h * NN;
    const int*   ar0 = adj + (size_t)i0 * NN;
    const int*   ar1 = adj + (size_t)i1 * NN;

    float m0 = -INFINITY, l0 = 0.f, m1 = -INFINITY, l1 = 0.f;   // base-2 units
    float acc0[NF], acc1[NF];
    #pragma unroll
    for (int f = 0; f < NF; ++f) { acc0[f] = 0.f; acc1[f] = 0.f; }

    for (int tt = 0; tt < NTILE; ++tt) {
        const int j = tt * 64 + lane;
        const float4* pg = (const float4*)(glh + (size_t)j * NF);
        const float4* pr = (const float4*)(grh + (size_t)j * NF);
        float4 g[4], r[4];
        g[0] = pg[0]; g[1] = pg[1]; g[2] = pg[2]; g[3] = pg[3];
        r[0] = pr[0]; r[1] = pr[1]; r[2] = pr[2]; r[3] = pr[3];
        const float cj = cjh[j];
        const int   a0 = ar0[j];
        const int   a1 = ar1[j];

        float s0 = 0.f, s1 = 0.f;
        #pragma unroll
        for (int q = 0; q < 4; ++q) {
            const float4 v = g[q];
            s0 = fmaf(fabsf(v.x + g0_s[q * 4 + 0]), aw_s[q * 4 + 0], s0);
            s0 = fmaf(fabsf(v.y + g0_s[q * 4 + 1]), aw_s[q * 4 + 1], s0);
            s0 = fmaf(fabsf(v.z + g0_s[q * 4 + 2]), aw_s[q * 4 + 2], s0);
            s0 = fmaf(fabsf(v.w + g0_s[q * 4 + 3]), aw_s[q * 4 + 3], s0);
            s1 = fmaf(fabsf(v.x + g1_s[q * 4 + 0]), aw_s[q * 4 + 0], s1);
            s1 = fmaf(fabsf(v.y + g1_s[q * 4 + 1]), aw_s[q * 4 + 1], s1);
            s1 = fmaf(fabsf(v.z + g1_s[q * 4 + 2]), aw_s[q * 4 + 2], s1);
            s1 = fmaf(fabsf(v.w + g1_s[q * 4 + 3]), aw_s[q * 4 + 3], s1);
        }
        const float e0 = s0 + (bi0 + cj);
        const float e1 = s1 + (bi1 + cj);
        const bool  k0 = (a0 != 0);
        const bool  k1 = (a1 != 0);
        const float f0 = k0 ? e0 : -INFINITY;
        const float f1 = k1 ? e1 : -INFINITY;

        if (__any((f0 > m0 + 11.5417f) || (f1 > m1 + 11.5417f))) {  // rare deferred rescale
            const bool  c0 = f0 > m0 + 11.5417f;
            const bool  c1 = f1 > m1 + 11.5417f;
            const float al0 = c0 ? __builtin_amdgcn_exp2f(m0 - f0) : 1.f;
            const float al1 = c1 ? __builtin_amdgcn_exp2f(m1 - f1) : 1.f;
            m0 = c0 ? f0 : m0;  m1 = c1 ? f1 : m1;
            l0 *= al0;          l1 *= al1;
            #pragma unroll
            for (int f = 0; f < NF; ++f) { acc0[f] *= al0; acc1[f] *= al1; }
        }
        const float p0 = k0 ? __builtin_amdgcn_exp2f(e0 - m0) : 0.f;
        const float p1 = k1 ? __builtin_amdgcn_exp2f(e1 - m1) : 0.f;
        l0 += p0;  l1 += p1;
        #pragma unroll
        for (int q = 0; q < 4; ++q) {
            const float4 v = r[q];
            acc0[q * 4 + 0] = fmaf(p0, v.x, acc0[q * 4 + 0]);
            acc0[q * 4 + 1] = fmaf(p0, v.y, acc0[q * 4 + 1]);
            acc0[q * 4 + 2] = fmaf(p0, v.z, acc0[q * 4 + 2]);
            acc0[q * 4 + 3] = fmaf(p0, v.w, acc0[q * 4 + 3]);
            acc1[q * 4 + 0] = fmaf(p1, v.x, acc1[q * 4 + 0]);
            acc1[q * 4 + 1] = fmaf(p1, v.y, acc1[q * 4 + 1]);
            acc1[q * 4 + 2] = fmaf(p1, v.z, acc1[q * 4 + 2]);
            acc1[q * 4 + 3] = fmaf(p1, v.w, acc1[q * 4 + 3]);
        }
    }

    // ---- merge (m, l, acc) across the 64 lanes, for both nodes ----
    float M0 = m0, M1 = m1;
    #pragma unroll
    for (int off = 32; off; off >>= 1) {
        M0 = fmaxf(M0, __shfl_xor(M0, off));
        M1 = fmaxf(M1, __shfl_xor(M1, off));
    }
    const float sc0 = (m0 > -INFINITY) ? __builtin_amdgcn_exp2f(m0 - M0) : 0.f;
    const float sc1 = (m1 > -INFINITY) ? __builtin_amdgcn_exp2f(m1 - M1) : 0.f;
    l0 *= sc0;  l1 *= sc1;
    #pragma unroll
    for (int off = 32; off; off >>= 1) {
        l0 += __shfl_xor(l0, off);
        l1 += __shfl_xor(l1, off);
    }

    __shared__ float red[8][2][16][NF + 1];
    #pragma unroll
    for (int f = 0; f < NF; ++f) {
        float a = acc0[f] * sc0;
        a += __shfl_xor(a, 32);
        a += __shfl_xor(a, 16);
        if (lane < 16) red[wid][0][lane][f] = a;
        float b = acc1[f] * sc1;
        b += __shfl_xor(b, 32);
        b += __shfl_xor(b, 16);
        if (lane < 16) red[wid][1][lane][f] = b;
    }
    __syncthreads();
    if (lane < NF) {
        float s = 0.f;
        #pragma unroll
        for (int r = 0; r < 16; ++r) s += red[wid][0][r][lane];
        out[i0 * OF + h * NF + lane] = (l0 > 0.f) ? s / l0 : 0.f;
    } else if (lane >= 32 && lane < 32 + NF) {
        float s = 0.f;
        #pragma unroll
        for (int r = 0; r < 16; ++r) s += red[wid][1][r][lane - 32];
        out[i1 * OF + h * NF + lane - 32] = (l1 > 0.f) ? s / l1 : 0.f;
    }
}

// tiny helper: scale attn_w into ws (aw_scaled[f] = attn_w[f] * 0.4*log2e)
__global__ void aw_kernel(const float* __restrict__ attn_w, float* __restrict__ aws) {
    if (threadIdx.x < NF) aws[threadIdx.x] = attn_w[threadIdx.x] * (0.4f * LOG2E);
}

extern "C" void kernel_launch(void* const* d_in, const int* in_sizes, int n_in,
                              void* d_out, int out_size, void* d_ws, size_t ws_size,
                              hipStream_t stream) {
    const float* h      = (const float*)d_in[0];
    const int*   adj    = (const int*)d_in[1];
    const float* W_l    = (const float*)d_in[2];
    const float* W_r    = (const float*)d_in[3];
    const float* attn_w = (const float*)d_in[4];
    float*       out    = (float*)d_out;

    float* glt = (float*)d_ws;                    // [NH][NN][NF]
    float* grt = glt + (size_t)NN * OF;           // [NH][NN][NF]
    float* cj6 = grt + (size_t)NN * OF;           // [NH][NN]
    float* bi6 = cj6 + (size_t)NH * NN;           // [NH][NN]
    float* aws = bi6 + (size_t)NH * NN;           // [NF]   (gat_kernel reads bi6 + NH*NN)

    aw_kernel<<<1, 64, 0, stream>>>(attn_w, aws);
    proj_kernel<<<NN / 2, 256, 0, stream>>>(h, W_l, W_r, attn_w, glt, grt, cj6, bi6);
    gat_kernel<<<NH * 128, 512, 0, stream>>>(glt, grt, cj6, bi6, adj, out);
}

// Round 6
// 58.883 us; speedup vs baseline: 2.5479x; 1.4160x over previous
//
#include <hip/hip_runtime.h>
#include <math.h>
#include <stdint.h>

#define NN 2048   // nodes
#define IF 128    // in features
#define NH 4      // heads
#define NF 16     // hidden per head
#define OF 64     // NH*NF
#define NTILE (NN / 64)   // 32 j-tiles of 64
#define LOG2E 1.44269504f

__device__ __forceinline__ float rfl(float x) {   // force wave-uniform value into SGPR
    return __int_as_float(__builtin_amdgcn_readfirstlane(__float_as_int(x)));
}

// async global->LDS, zero VGPR round-trip. dst is wave-uniform base; HW writes
// lane L at dst + L*size; src is per-lane.
__device__ __forceinline__ void gl2lds16(const void* g, void* l) {
    __builtin_amdgcn_global_load_lds((const __attribute__((address_space(1))) void*)g,
                                     (__attribute__((address_space(3))) void*)l, 16, 0, 0);
}
__device__ __forceinline__ void gl2lds4(const void* g, void* l) {
    __builtin_amdgcn_global_load_lds((const __attribute__((address_space(1))) void*)g,
                                     (__attribute__((address_space(3))) void*)l, 4, 0, 0);
}

// ---------------- Kernel 1: projections (head-major) + attention-bias precompute ----------------
// glt/grt [NH][NN][NF] head-major; cj6[h][j] = 0.6*log2e*sum_f aw_f*glt[h,j,f], bi6 from grt.
__global__ __launch_bounds__(256) void proj_kernel(const float* __restrict__ h,
                                                   const float* __restrict__ Wl,
                                                   const float* __restrict__ Wr,
                                                   const float* __restrict__ attn_w,
                                                   float* __restrict__ glt,
                                                   float* __restrict__ grt,
                                                   float* __restrict__ cj6,
                                                   float* __restrict__ bi6) {
    const int t    = threadIdx.x;
    const int w    = t >> 6, lane = t & 63;
    const int il   = w >> 1, which = w & 1;          // which: 0 = W_l, 1 = W_r
    const int i    = blockIdx.x * 2 + il;

    __shared__ float hs[2][IF];
    hs[t >> 7][t & 127] = h[(blockIdx.x * 2 + (t >> 7)) * IF + (t & 127)];
    __syncthreads();

    const float* W = which ? Wr : Wl;
    float acc = 0.f;
    #pragma unroll
    for (int k = 0; k < IF; ++k)
        acc = fmaf(hs[il][k], W[k * OF + lane], acc);   // coalesced W read per wave

    float* g = which ? grt : glt;
    g[(lane >> 4) * (NN * NF) + i * NF + (lane & 15)] = acc;

    float v = acc * attn_w[lane & 15];
    v += __shfl_xor(v, 1);
    v += __shfl_xor(v, 2);
    v += __shfl_xor(v, 4);
    v += __shfl_xor(v, 8);
    if ((lane & 15) == 0) {
        float* dst = which ? bi6 : cj6;
        dst[(lane >> 4) * NN + i] = 0.6f * LOG2E * v;
    }
}

// ---------------- Kernel 2: fused flash GAT, LDS-staged double-buffered tiles ----------------
// grid NH*128, block 512 (8 waves, all same head h = bx>>7), 16 nodes/block (2/wave).
// Per step: async-stage next tile (g 4KB + r 4KB + adj 4KB + cj 256B) into LDS buf^1 via
// global_load_lds (no VGPRs, in flight during compute), compute current tile from LDS,
// one __syncthreads (drains stage + syncs buffers). Source-side chunk-XOR swizzle makes
// the ds_read_b128 pattern bank-balanced (8 accesses/bank = minimum).
__global__ __launch_bounds__(512, 4) void gat_kernel(const float* __restrict__ glt,
                                                     const float* __restrict__ grt,
                                                     const float* __restrict__ cj6,
                                                     const float* __restrict__ bi6,
                                                     const int*   __restrict__ adj,
                                                     const float* __restrict__ attn_w,
                                                     float*       __restrict__ out) {
    const int t    = threadIdx.x;
    const int wid  = t >> 6, lane = t & 63;
    const int h    = blockIdx.x >> 7;
    const int grp  = blockIdx.x & 127;
    const int i0   = grp * 16 + wid * 2;
    const int i1   = i0 + 1;

    __shared__ __attribute__((aligned(16))) float g_s[2][64 * NF];  // swizzled tiles
    __shared__ __attribute__((aligned(16))) float r_s[2][64 * NF];
    __shared__ int   a_s[2][16][64];
    __shared__ float c_s[2][64];
    __shared__ float red[8][2][16][NF + 1];

    // wave-uniform constants -> SGPR
    float aw_s[NF], g0_s[NF], g1_s[NF];
    #pragma unroll
    for (int f = 0; f < NF; ++f) {
        aw_s[f] = rfl(attn_w[f]) * (0.4f * LOG2E);
        g0_s[f] = rfl(grt[h * (NN * NF) + i0 * NF + f]);
        g1_s[f] = rfl(grt[h * (NN * NF) + i1 * NF + f]);
    }
    const float bi0 = rfl(bi6[h * NN + i0]);
    const float bi1 = rfl(bi6[h * NN + i1]);

    const float* glh = glt + (size_t)h * NN * NF;
    const float* grh = grt + (size_t)h * NN * NF;
    const float* cjh = cj6 + h * NN;

    // staging geometry: wave ww covers 16 rows; lane L -> row ww*16+(L>>2), slot L&3,
    // source chunk q = (L&3) ^ ((L>>3)&3)  (== slot ^ ((row>>1)&3), since ww*8 % 4 == 0)
    const int ww   = wid & 3;
    const int soff = (ww * 16 + (lane >> 2)) * NF + (((lane & 3) ^ ((lane >> 3) & 3)) << 2);

#define STAGE(tile, nb)                                                          \
    {                                                                            \
        const float* gt = glh + (size_t)(tile) * 64 * NF;                        \
        const float* rt = grh + (size_t)(tile) * 64 * NF;                        \
        if (wid < 4) gl2lds16(gt + soff, &g_s[nb][ww * 16 * NF]);                \
        else         gl2lds16(rt + soff, &r_s[nb][ww * 16 * NF]);                \
        gl2lds4(adj + (size_t)i0 * NN + (tile) * 64 + lane, &a_s[nb][wid*2][0]); \
        gl2lds4(adj + (size_t)i1 * NN + (tile) * 64 + lane, &a_s[nb][wid*2+1][0]);\
        if (wid == 0) gl2lds4(cjh + (tile) * 64 + lane, &c_s[nb][0]);            \
    }

    float m0 = -INFINITY, l0 = 0.f, m1 = -INFINITY, l1 = 0.f;   // base-2 units
    float acc0[NF], acc1[NF];
    #pragma unroll
    for (int f = 0; f < NF; ++f) { acc0[f] = 0.f; acc1[f] = 0.f; }

    STAGE(0, 0);
    __syncthreads();

    for (int tt = 0; tt < NTILE; ++tt) {
        const int buf = tt & 1;
        if (tt + 1 < NTILE) STAGE(tt + 1, buf ^ 1);

        // this lane's row j = tt*64 + lane, de-swizzled chunk reads
        float4 g[4], r[4];
        #pragma unroll
        for (int q = 0; q < 4; ++q) {
            const int c = q ^ ((lane >> 1) & 3);
            g[q] = *(const float4*)&g_s[buf][lane * NF + c * 4];
            r[q] = *(const float4*)&r_s[buf][lane * NF + c * 4];
        }
        const float cj = c_s[buf][lane];
        const int   a0 = a_s[buf][wid * 2][lane];
        const int   a1 = a_s[buf][wid * 2 + 1][lane];

        float s0 = 0.f, s1 = 0.f;
        #pragma unroll
        for (int q = 0; q < 4; ++q) {
            const float4 v = g[q];
            s0 = fmaf(fabsf(v.x + g0_s[q * 4 + 0]), aw_s[q * 4 + 0], s0);
            s0 = fmaf(fabsf(v.y + g0_s[q * 4 + 1]), aw_s[q * 4 + 1], s0);
            s0 = fmaf(fabsf(v.z + g0_s[q * 4 + 2]), aw_s[q * 4 + 2], s0);
            s0 = fmaf(fabsf(v.w + g0_s[q * 4 + 3]), aw_s[q * 4 + 3], s0);
            s1 = fmaf(fabsf(v.x + g1_s[q * 4 + 0]), aw_s[q * 4 + 0], s1);
            s1 = fmaf(fabsf(v.y + g1_s[q * 4 + 1]), aw_s[q * 4 + 1], s1);
            s1 = fmaf(fabsf(v.z + g1_s[q * 4 + 2]), aw_s[q * 4 + 2], s1);
            s1 = fmaf(fabsf(v.w + g1_s[q * 4 + 3]), aw_s[q * 4 + 3], s1);
        }
        const float e0 = s0 + (bi0 + cj);
        const float e1 = s1 + (bi1 + cj);
        const bool  k0 = (a0 != 0);
        const bool  k1 = (a1 != 0);
        const float f0 = k0 ? e0 : -INFINITY;
        const float f1 = k1 ? e1 : -INFINITY;

        if (__any((f0 > m0 + 11.5417f) || (f1 > m1 + 11.5417f))) {  // rare deferred rescale
            const bool  c0 = f0 > m0 + 11.5417f;
            const bool  c1 = f1 > m1 + 11.5417f;
            const float al0 = c0 ? __builtin_amdgcn_exp2f(m0 - f0) : 1.f;
            const float al1 = c1 ? __builtin_amdgcn_exp2f(m1 - f1) : 1.f;
            m0 = c0 ? f0 : m0;  m1 = c1 ? f1 : m1;
            l0 *= al0;          l1 *= al1;
            #pragma unroll
            for (int f = 0; f < NF; ++f) { acc0[f] *= al0; acc1[f] *= al1; }
        }
        const float p0 = k0 ? __builtin_amdgcn_exp2f(e0 - m0) : 0.f;
        const float p1 = k1 ? __builtin_amdgcn_exp2f(e1 - m1) : 0.f;
        l0 += p0;  l1 += p1;
        #pragma unroll
        for (int q = 0; q < 4; ++q) {
            const float4 v = r[q];
            acc0[q * 4 + 0] = fmaf(p0, v.x, acc0[q * 4 + 0]);
            acc0[q * 4 + 1] = fmaf(p0, v.y, acc0[q * 4 + 1]);
            acc0[q * 4 + 2] = fmaf(p0, v.z, acc0[q * 4 + 2]);
            acc0[q * 4 + 3] = fmaf(p0, v.w, acc0[q * 4 + 3]);
            acc1[q * 4 + 0] = fmaf(p1, v.x, acc1[q * 4 + 0]);
            acc1[q * 4 + 1] = fmaf(p1, v.y, acc1[q * 4 + 1]);
            acc1[q * 4 + 2] = fmaf(p1, v.z, acc1[q * 4 + 2]);
            acc1[q * 4 + 3] = fmaf(p1, v.w, acc1[q * 4 + 3]);
        }
        __syncthreads();   // drains stage(t+1) vmcnt + protects buf swap
    }
#undef STAGE

    // ---- merge (m, l, acc) across the 64 lanes, for both nodes ----
    float M0 = m0, M1 = m1;
    #pragma unroll
    for (int off = 32; off; off >>= 1) {
        M0 = fmaxf(M0, __shfl_xor(M0, off));
        M1 = fmaxf(M1, __shfl_xor(M1, off));
    }
    const float sc0 = (m0 > -INFINITY) ? __builtin_amdgcn_exp2f(m0 - M0) : 0.f;
    const float sc1 = (m1 > -INFINITY) ? __builtin_amdgcn_exp2f(m1 - M1) : 0.f;
    l0 *= sc0;  l1 *= sc1;
    #pragma unroll
    for (int off = 32; off; off >>= 1) {
        l0 += __shfl_xor(l0, off);
        l1 += __shfl_xor(l1, off);
    }

    #pragma unroll
    for (int f = 0; f < NF; ++f) {
        float a = acc0[f] * sc0;
        a += __shfl_xor(a, 32);
        a += __shfl_xor(a, 16);
        if (lane < 16) red[wid][0][lane][f] = a;
        float b = acc1[f] * sc1;
        b += __shfl_xor(b, 32);
        b += __shfl_xor(b, 16);
        if (lane < 16) red[wid][1][lane][f] = b;
    }
    __syncthreads();
    if (lane < NF) {
        float s = 0.f;
        #pragma unroll
        for (int r = 0; r < 16; ++r) s += red[wid][0][r][lane];
        out[i0 * OF + h * NF + lane] = (l0 > 0.f) ? s / l0 : 0.f;
    } else if (lane >= 32 && lane < 32 + NF) {
        float s = 0.f;
        #pragma unroll
        for (int r = 0; r < 16; ++r) s += red[wid][1][r][lane - 32];
        out[i1 * OF + h * NF + lane - 32] = (l1 > 0.f) ? s / l1 : 0.f;
    }
}

extern "C" void kernel_launch(void* const* d_in, const int* in_sizes, int n_in,
                              void* d_out, int out_size, void* d_ws, size_t ws_size,
                              hipStream_t stream) {
    const float* h      = (const float*)d_in[0];
    const int*   adj    = (const int*)d_in[1];
    const float* W_l    = (const float*)d_in[2];
    const float* W_r    = (const float*)d_in[3];
    const float* attn_w = (const float*)d_in[4];
    float*       out    = (float*)d_out;

    float* glt = (float*)d_ws;                    // [NH][NN][NF]
    float* grt = glt + (size_t)NN * OF;           // [NH][NN][NF]
    float* cj6 = grt + (size_t)NN * OF;           // [NH][NN]
    float* bi6 = cj6 + (size_t)NH * NN;           // [NH][NN]

    proj_kernel<<<NN / 2, 256, 0, stream>>>(h, W_l, W_r, attn_w, glt, grt, cj6, bi6);
    gat_kernel<<<NH * 128, 512, 0, stream>>>(glt, grt, cj6, bi6, adj, attn_w, out);
}